// Round 5
// baseline (270.119 us; speedup 1.0000x reference)
//
#include <hip/hip_runtime.h>

#define D_IN 256
#define D_HID 128

typedef __bf16 bf16;
typedef bf16 bf16x8 __attribute__((ext_vector_type(8)));
typedef bf16 bf16x4 __attribute__((ext_vector_type(4)));
typedef float f32x4 __attribute__((ext_vector_type(4)));
typedef unsigned long long u64;
typedef u64 u64x2 __attribute__((ext_vector_type(2)));

// ---------------- CSR build (dst-sorted) ----------------
__global__ void k_hist(const int* __restrict__ dst, int E, int* __restrict__ deg) {
  int e = blockIdx.x * blockDim.x + threadIdx.x;
  if (e < E) atomicAdd(&deg[dst[e]], 1);
}

__global__ void k_blocksum(const int* __restrict__ deg, int N, int* __restrict__ bsum) {
  __shared__ int sm[512];
  int i = blockIdx.x * 512 + threadIdx.x;
  sm[threadIdx.x] = (i < N) ? deg[i] : 0;
  __syncthreads();
  for (int off = 256; off > 0; off >>= 1) {
    if (threadIdx.x < off) sm[threadIdx.x] += sm[threadIdx.x + off];
    __syncthreads();
  }
  if (threadIdx.x == 0) bsum[blockIdx.x] = sm[0];
}

__global__ void k_scan_partials(const int* __restrict__ bsum, int nch,
                                int* __restrict__ boff,
                                int* __restrict__ row_ptr, int N, int E) {
  __shared__ int sm[128];
  int t = threadIdx.x;
  int v = (t < nch) ? bsum[t] : 0;
  int x = v;
  sm[t] = x; __syncthreads();
  for (int off = 1; off < 128; off <<= 1) {
    int u = (t >= off) ? sm[t - off] : 0;
    __syncthreads();
    x += u; sm[t] = x; __syncthreads();
  }
  if (t < nch) boff[t] = x - v;
  if (t == 0) row_ptr[N] = E;
}

__global__ void k_scan_final(const int* __restrict__ deg, int N,
                             const int* __restrict__ boff,
                             int* __restrict__ row_ptr, int* __restrict__ cursor) {
  __shared__ int sm[512];
  int t = threadIdx.x;
  int i = blockIdx.x * 512 + t;
  int v = (i < N) ? deg[i] : 0;
  int x = v;
  sm[t] = x; __syncthreads();
  for (int off = 1; off < 512; off <<= 1) {
    int u = (t >= off) ? sm[t - off] : 0;
    __syncthreads();
    x += u; sm[t] = x; __syncthreads();
  }
  if (i < N) {
    int ex = x - v + boff[blockIdx.x];
    row_ptr[i] = ex;
    cursor[i]  = ex;
  }
}

__global__ void k_scatter(const int* __restrict__ src, const int* __restrict__ dst,
                          const float* __restrict__ ew, int E,
                          int* __restrict__ cursor, int2* __restrict__ esw) {
  int e = blockIdx.x * blockDim.x + threadIdx.x;
  if (e < E) {
    int d = dst[e];
    int p = atomicAdd(&cursor[d], 1);
    esw[p] = make_int2(src[e], __float_as_int(ew[e]));
  }
}

// ---------------- prep: zero deg + pack W->fragment-major bf16 + fcw transpose ----
// Bpack element r: e = r&7, lane = (r>>3)&63, f = r>>9; ct = f&7, kt = f>>3.
// Bpack[r] = W[kt*32 + 8*(lane>>4) + e][ct*16 + (lane&15)]
__global__ void k_prep(const float* __restrict__ W1, const float* __restrict__ W2,
                       const float* __restrict__ W3, const float* __restrict__ fcw,
                       bf16* __restrict__ B1, bf16* __restrict__ B2,
                       bf16* __restrict__ B3, float* __restrict__ fcwT,
                       int* __restrict__ deg, int N) {
  int idx = blockIdx.x * blockDim.x + threadIdx.x;
  {
    const float* W; bf16* B; int r;
    if (idx < 32768)      { W = W1; B = B1; r = idx; }
    else if (idx < 49152) { W = W2; B = B2; r = idx - 32768; }
    else                  { W = W3; B = B3; r = idx - 49152; }
    int e = r & 7, l = (r >> 3) & 63, f = r >> 9;
    int ct = f & 7, kt = f >> 3;
    int k = kt * 32 + ((l >> 4) << 3) + e;
    int c = ct * 16 + (l & 15);
    B[r] = (bf16)W[k * 128 + c];
  }
  if (idx < 2048) {
    int c = idx >> 7, k = idx & 127;
    fcwT[idx] = fcw[k * 16 + c];
  }
  if (idx < N) deg[idx] = 0;
}

// ---------------- MFMA GEMM: H[N,128] = A[N,K] @ W[K,128] ----------------
// 512 threads = 8 waves, 128 rows/block (16 rows/wave). B staged in LDS in
// 32KB chunks (fragment-major) -> ds_read_b128 B fragments, no miss latency.
template<int K, bool A_IS_F32>
__global__ __launch_bounds__(512) void k_gemm2(const void* __restrict__ Ain,
                                               const bf16* __restrict__ Bp,
                                               bf16* __restrict__ Hb, int N) {
  constexpr int NCH = K / 128;            // 32KB chunks of B
  __shared__ bf16 Bs[128 * 128];          // 32 KB
  const int t = threadIdx.x;
  const int wave = t >> 6;
  const int lane = t & 63;
  const int l16 = lane & 15;
  const int g = lane >> 4;
  const int row0 = blockIdx.x * 128 + wave * 16;
  const int arow = row0 + l16;
  const int arow_c = (arow < N) ? arow : (N - 1);

  f32x4 acc[8];
  #pragma unroll
  for (int ct = 0; ct < 8; ++ct) acc[ct] = f32x4{0.f, 0.f, 0.f, 0.f};

  for (int kc = 0; kc < NCH; ++kc) {
    if (kc) __syncthreads();
    // stage 32KB: 2048 x 16B, 4 per thread
    const u64x2* src = reinterpret_cast<const u64x2*>(Bp + (size_t)kc * 128 * 128);
    u64x2* dstl = reinterpret_cast<u64x2*>(Bs);
    #pragma unroll
    for (int i = 0; i < 4; ++i) dstl[t + i * 512] = src[t + i * 512];
    __syncthreads();

    // A fragments for this chunk (4 kt), hoisted
    bf16x8 afr[4];
    if constexpr (A_IS_F32) {
      const float* Af = (const float*)Ain + (size_t)arow_c * K + kc * 128 + g * 8;
      #pragma unroll
      for (int kt = 0; kt < 4; ++kt) {
        f32x4 f0 = *reinterpret_cast<const f32x4*>(Af + kt * 32);
        f32x4 f1 = *reinterpret_cast<const f32x4*>(Af + kt * 32 + 4);
        bf16x8 a;
        a[0] = (bf16)f0[0]; a[1] = (bf16)f0[1]; a[2] = (bf16)f0[2]; a[3] = (bf16)f0[3];
        a[4] = (bf16)f1[0]; a[5] = (bf16)f1[1]; a[6] = (bf16)f1[2]; a[7] = (bf16)f1[3];
        afr[kt] = a;
      }
    } else {
      const bf16* Ab = (const bf16*)Ain + (size_t)arow_c * K + kc * 128 + g * 8;
      #pragma unroll
      for (int kt = 0; kt < 4; ++kt)
        afr[kt] = *reinterpret_cast<const bf16x8*>(Ab + kt * 32);
    }

    #pragma unroll
    for (int kt = 0; kt < 4; ++kt) {
      #pragma unroll
      for (int ct = 0; ct < 8; ++ct) {
        bf16x8 b = *reinterpret_cast<const bf16x8*>(Bs + (kt * 8 + ct) * 512 + lane * 8);
        acc[ct] = __builtin_amdgcn_mfma_f32_16x16x32_bf16(afr[kt], b, acc[ct], 0, 0, 0);
      }
    }
  }

  const int orow = row0 + 4 * g;
  #pragma unroll
  for (int ct = 0; ct < 8; ++ct) {
    #pragma unroll
    for (int r = 0; r < 4; ++r) {
      if (orow + r < N)
        Hb[(size_t)(orow + r) * 128 + ct * 16 + l16] = (bf16)acc[ct][r];
    }
  }
}

// ---------------- aggregation: out[n,:] = sum_e w_e * H[src_e,:] + b ----------------
template<int MODE>
__global__ __launch_bounds__(256) void k_agg(const bf16* __restrict__ H,
                                             const int* __restrict__ rptr,
                                             const int2* __restrict__ esw,
                                             const float* __restrict__ bias,
                                             void* __restrict__ out, int N) {
  const int node = blockIdx.x * 4 + (threadIdx.x >> 6);
  if (node >= N) return;
  const int lane = threadIdx.x & 63;
  const int l31 = lane & 31;
  const int half = lane >> 5;
  const int p1 = rptr[node + 1];
  float a0 = 0.f, a1 = 0.f, a2 = 0.f, a3 = 0.f;
  int p = rptr[node] + half;
  for (; p + 2 < p1; p += 4) {
    int2 e0 = esw[p];
    int2 e1 = esw[p + 2];
    bf16x4 h0 = *reinterpret_cast<const bf16x4*>(H + (size_t)e0.x * 128 + l31 * 4);
    bf16x4 h1 = *reinterpret_cast<const bf16x4*>(H + (size_t)e1.x * 128 + l31 * 4);
    float w0 = __int_as_float(e0.y), w1 = __int_as_float(e1.y);
    a0 += w0 * (float)h0[0] + w1 * (float)h1[0];
    a1 += w0 * (float)h0[1] + w1 * (float)h1[1];
    a2 += w0 * (float)h0[2] + w1 * (float)h1[2];
    a3 += w0 * (float)h0[3] + w1 * (float)h1[3];
  }
  if (p < p1) {
    int2 e0 = esw[p];
    bf16x4 h0 = *reinterpret_cast<const bf16x4*>(H + (size_t)e0.x * 128 + l31 * 4);
    float w0 = __int_as_float(e0.y);
    a0 += w0 * (float)h0[0];
    a1 += w0 * (float)h0[1];
    a2 += w0 * (float)h0[2];
    a3 += w0 * (float)h0[3];
  }
  a0 += __shfl_xor(a0, 32);
  a1 += __shfl_xor(a1, 32);
  a2 += __shfl_xor(a2, 32);
  a3 += __shfl_xor(a3, 32);
  if (half == 0) {
    float4 bv = *reinterpret_cast<const float4*>(bias + l31 * 4);
    a0 += bv.x; a1 += bv.y; a2 += bv.z; a3 += bv.w;
    if (MODE == 0) {
      bf16x4 o;
      o[0] = (bf16)fmaxf(a0, 0.f); o[1] = (bf16)fmaxf(a1, 0.f);
      o[2] = (bf16)fmaxf(a2, 0.f); o[3] = (bf16)fmaxf(a3, 0.f);
      *reinterpret_cast<bf16x4*>((bf16*)out + (size_t)node * 128 + l31 * 4) = o;
    } else {
      f32x4 o = {a0, a1, a2, a3};
      *reinterpret_cast<f32x4*>((float*)out + (size_t)node * 128 + l31 * 4) = o;
    }
  }
}

// ---------------- fc + log_softmax (fcwT[c][k], float4-vectorized) ----------------
__global__ void k_fc_lsm(const float* __restrict__ emb, const float* __restrict__ fcwT,
                         const float* __restrict__ fcb, float* __restrict__ out, int N) {
  int t = threadIdx.x;
  int node = blockIdx.x * 16 + (t >> 4);
  int c = t & 15;
  if (node >= N) return;
  const float4* er4 = reinterpret_cast<const float4*>(emb + (size_t)node * 128);
  const float4* wt4 = reinterpret_cast<const float4*>(fcwT + c * 128);
  float acc = fcb[c];
  #pragma unroll
  for (int k4 = 0; k4 < 32; ++k4) {
    float4 e = er4[k4];
    float4 w = wt4[k4];
    acc += e.x * w.x + e.y * w.y + e.z * w.z + e.w * w.w;
  }
  float m = acc;
  #pragma unroll
  for (int off = 8; off >= 1; off >>= 1) m = fmaxf(m, __shfl_xor(m, off, 16));
  float e = __expf(acc - m);
  float s = e;
  #pragma unroll
  for (int off = 8; off >= 1; off >>= 1) s += __shfl_xor(s, off, 16);
  out[(size_t)node * 16 + c] = acc - m - __logf(s);
}

extern "C" void kernel_launch(void* const* d_in, const int* in_sizes, int n_in,
                              void* d_out, int out_size, void* d_ws, size_t ws_size,
                              hipStream_t stream) {
  const float* x   = (const float*)d_in[0];
  const float* ew  = (const float*)d_in[1];
  const float* W1  = (const float*)d_in[2];
  const float* b1  = (const float*)d_in[3];
  const float* W2  = (const float*)d_in[4];
  const float* b2  = (const float*)d_in[5];
  const float* W3  = (const float*)d_in[6];
  const float* b3  = (const float*)d_in[7];
  const float* fcw = (const float*)d_in[8];
  const float* fcb = (const float*)d_in[9];
  const int*   ei  = (const int*)d_in[10];

  const int N = in_sizes[0] / D_IN;     // 50000
  const int E = in_sizes[1];            // 625000
  const int* srcI = ei;
  const int* dstI = ei + E;

  char* ws = (char*)d_ws;
  size_t o = 0;
  auto take = [&](size_t b) -> char* {
    char* p = ws + o;
    o += (b + 255) & ~(size_t)255;
    return p;
  };
  bf16*  hb0  = (bf16*)take((size_t)N * 128 * 2);
  bf16*  hb1  = (bf16*)take((size_t)N * 128 * 2);
  bf16*  Bp1  = (bf16*)take((size_t)D_IN * 128 * 2);
  bf16*  Bp2  = (bf16*)take((size_t)D_HID * 128 * 2);
  bf16*  Bp3  = (bf16*)take((size_t)D_HID * 128 * 2);
  float* fcwT = (float*)take((size_t)2048 * 4);
  int*   deg  = (int*)take((size_t)N * 4);
  int*   rptr = (int*)take((size_t)(N + 1) * 4);
  int*   cur  = (int*)take((size_t)N * 4);
  int*   bsum = (int*)take(4096);
  int*   boff = (int*)take(4096);
  int2*  esw  = (int2*)take((size_t)E * 8);
  (void)ws_size; (void)n_in; (void)out_size;

  // prep: zero deg + pack weights (replaces hipMemsetAsync fill, which
  // showed up at ~40us in the dispatch stream)
  k_prep<<<256, 256, 0, stream>>>(W1, W2, W3, fcw, Bp1, Bp2, Bp3, fcwT, deg, N);

  // CSR build (once; reused by all 3 SpMM layers)
  int eb  = (E + 255) / 256;
  int nch = (N + 511) / 512;
  k_hist<<<eb, 256, 0, stream>>>(dstI, E, deg);
  k_blocksum<<<nch, 512, 0, stream>>>(deg, N, bsum);
  k_scan_partials<<<1, 128, 0, stream>>>(bsum, nch, boff, rptr, N, E);
  k_scan_final<<<nch, 512, 0, stream>>>(deg, N, boff, rptr, cur);
  k_scatter<<<eb, 256, 0, stream>>>(srcI, dstI, ew, E, cur, esw);

  float* emb = (float*)d_out;
  float* lsm = emb + (size_t)N * 128;
  int gb2 = (N + 127) / 128;
  int ab = (N + 3) / 4;

  k_gemm2<D_IN, true><<<gb2, 512, 0, stream>>>(x, Bp1, hb0, N);
  k_agg<0><<<ab, 256, 0, stream>>>(hb0, rptr, esw, b1, hb1, N);
  k_gemm2<D_HID, false><<<gb2, 512, 0, stream>>>(hb1, Bp2, hb0, N);
  k_agg<0><<<ab, 256, 0, stream>>>(hb0, rptr, esw, b2, hb1, N);
  k_gemm2<D_HID, false><<<gb2, 512, 0, stream>>>(hb1, Bp3, hb0, N);
  k_agg<1><<<ab, 256, 0, stream>>>(hb0, rptr, esw, b3, emb, N);
  k_fc_lsm<<<(N + 15) / 16, 256, 0, stream>>>(emb, fcwT, fcb, lsm, N);
}

// Round 6
// 216.029 us; speedup vs baseline: 1.2504x; 1.2504x over previous
//
#include <hip/hip_runtime.h>

#define D_IN 256
#define D_HID 128

typedef __bf16 bf16;
typedef bf16 bf16x8 __attribute__((ext_vector_type(8)));
typedef bf16 bf16x4 __attribute__((ext_vector_type(4)));
typedef float f32x4 __attribute__((ext_vector_type(4)));
typedef unsigned long long u64;
typedef u64 u64x2 __attribute__((ext_vector_type(2)));

// ---------------- CSR build (dst-sorted) ----------------
__global__ void k_hist(const int* __restrict__ dst, int E, int* __restrict__ deg) {
  int e = blockIdx.x * blockDim.x + threadIdx.x;
  if (e < E) atomicAdd(&deg[dst[e]], 1);
}

__global__ void k_blocksum(const int* __restrict__ deg, int N, int* __restrict__ bsum) {
  __shared__ int sm[512];
  int i = blockIdx.x * 512 + threadIdx.x;
  sm[threadIdx.x] = (i < N) ? deg[i] : 0;
  __syncthreads();
  for (int off = 256; off > 0; off >>= 1) {
    if (threadIdx.x < off) sm[threadIdx.x] += sm[threadIdx.x + off];
    __syncthreads();
  }
  if (threadIdx.x == 0) bsum[blockIdx.x] = sm[0];
}

__global__ void k_scan_partials(const int* __restrict__ bsum, int nch,
                                int* __restrict__ boff,
                                int* __restrict__ row_ptr, int N, int E) {
  __shared__ int sm[128];
  int t = threadIdx.x;
  int v = (t < nch) ? bsum[t] : 0;
  int x = v;
  sm[t] = x; __syncthreads();
  for (int off = 1; off < 128; off <<= 1) {
    int u = (t >= off) ? sm[t - off] : 0;
    __syncthreads();
    x += u; sm[t] = x; __syncthreads();
  }
  if (t < nch) boff[t] = x - v;
  if (t == 0) row_ptr[N] = E;
}

__global__ void k_scan_final(const int* __restrict__ deg, int N,
                             const int* __restrict__ boff,
                             int* __restrict__ row_ptr, int* __restrict__ cursor) {
  __shared__ int sm[512];
  int t = threadIdx.x;
  int i = blockIdx.x * 512 + t;
  int v = (i < N) ? deg[i] : 0;
  int x = v;
  sm[t] = x; __syncthreads();
  for (int off = 1; off < 512; off <<= 1) {
    int u = (t >= off) ? sm[t - off] : 0;
    __syncthreads();
    x += u; sm[t] = x; __syncthreads();
  }
  if (i < N) {
    int ex = x - v + boff[blockIdx.x];
    row_ptr[i] = ex;
    cursor[i]  = ex;
  }
}

__global__ void k_scatter(const int* __restrict__ src, const int* __restrict__ dst,
                          const float* __restrict__ ew, int E,
                          int* __restrict__ cursor, int2* __restrict__ esw) {
  int e = blockIdx.x * blockDim.x + threadIdx.x;
  if (e < E) {
    int d = dst[e];
    int p = atomicAdd(&cursor[d], 1);
    esw[p] = make_int2(src[e], __float_as_int(ew[e]));
  }
}

// ---------------- prep: zero deg + pack W->fragment-major bf16 + fcw transpose ----
__global__ void k_prep(const float* __restrict__ W1, const float* __restrict__ W2,
                       const float* __restrict__ W3, const float* __restrict__ fcw,
                       bf16* __restrict__ B1, bf16* __restrict__ B2,
                       bf16* __restrict__ B3, float* __restrict__ fcwT,
                       int* __restrict__ deg, int N) {
  int idx = blockIdx.x * blockDim.x + threadIdx.x;
  {
    const float* W; bf16* B; int r;
    if (idx < 32768)      { W = W1; B = B1; r = idx; }
    else if (idx < 49152) { W = W2; B = B2; r = idx - 32768; }
    else                  { W = W3; B = B3; r = idx - 49152; }
    int e = r & 7, l = (r >> 3) & 63, f = r >> 9;
    int ct = f & 7, kt = f >> 3;
    int k = kt * 32 + ((l >> 4) << 3) + e;
    int c = ct * 16 + (l & 15);
    B[r] = (bf16)W[k * 128 + c];
  }
  if (idx < 2048) {
    int c = idx >> 7, k = idx & 127;
    fcwT[idx] = fcw[k * 16 + c];
  }
  if (idx < N) deg[idx] = 0;
}

// ---------------- MFMA GEMM: H[N,128] = A[N,K] @ W[K,128] ----------------
template<int K, bool A_IS_F32>
__global__ __launch_bounds__(512) void k_gemm2(const void* __restrict__ Ain,
                                               const bf16* __restrict__ Bp,
                                               bf16* __restrict__ Hb, int N) {
  constexpr int NCH = K / 128;
  __shared__ bf16 Bs[128 * 128];          // 32 KB
  const int t = threadIdx.x;
  const int wave = t >> 6;
  const int lane = t & 63;
  const int l16 = lane & 15;
  const int g = lane >> 4;
  const int row0 = blockIdx.x * 128 + wave * 16;
  const int arow = row0 + l16;
  const int arow_c = (arow < N) ? arow : (N - 1);

  f32x4 acc[8];
  #pragma unroll
  for (int ct = 0; ct < 8; ++ct) acc[ct] = f32x4{0.f, 0.f, 0.f, 0.f};

  for (int kc = 0; kc < NCH; ++kc) {
    if (kc) __syncthreads();
    const u64x2* src = reinterpret_cast<const u64x2*>(Bp + (size_t)kc * 128 * 128);
    u64x2* dstl = reinterpret_cast<u64x2*>(Bs);
    #pragma unroll
    for (int i = 0; i < 4; ++i) dstl[t + i * 512] = src[t + i * 512];
    __syncthreads();

    bf16x8 afr[4];
    if constexpr (A_IS_F32) {
      const float* Af = (const float*)Ain + (size_t)arow_c * K + kc * 128 + g * 8;
      #pragma unroll
      for (int kt = 0; kt < 4; ++kt) {
        f32x4 f0 = *reinterpret_cast<const f32x4*>(Af + kt * 32);
        f32x4 f1 = *reinterpret_cast<const f32x4*>(Af + kt * 32 + 4);
        bf16x8 a;
        a[0] = (bf16)f0[0]; a[1] = (bf16)f0[1]; a[2] = (bf16)f0[2]; a[3] = (bf16)f0[3];
        a[4] = (bf16)f1[0]; a[5] = (bf16)f1[1]; a[6] = (bf16)f1[2]; a[7] = (bf16)f1[3];
        afr[kt] = a;
      }
    } else {
      const bf16* Ab = (const bf16*)Ain + (size_t)arow_c * K + kc * 128 + g * 8;
      #pragma unroll
      for (int kt = 0; kt < 4; ++kt)
        afr[kt] = *reinterpret_cast<const bf16x8*>(Ab + kt * 32);
    }

    #pragma unroll
    for (int kt = 0; kt < 4; ++kt) {
      #pragma unroll
      for (int ct = 0; ct < 8; ++ct) {
        bf16x8 b = *reinterpret_cast<const bf16x8*>(Bs + (kt * 8 + ct) * 512 + lane * 8);
        acc[ct] = __builtin_amdgcn_mfma_f32_16x16x32_bf16(afr[kt], b, acc[ct], 0, 0, 0);
      }
    }
  }

  const int orow = row0 + 4 * g;
  #pragma unroll
  for (int ct = 0; ct < 8; ++ct) {
    #pragma unroll
    for (int r = 0; r < 4; ++r) {
      if (orow + r < N)
        Hb[(size_t)(orow + r) * 128 + ct * 16 + l16] = (bf16)acc[ct][r];
    }
  }
}

// ---------------- aggregation: out[n,:] = sum_e w_e * H[src_e,:] + b ----------------
// Quarter-wave rows: 16 lanes x bf16x8 (16B) cover one 256B row. A wave serves
// 2 nodes x 2 edge-slots; 2x unroll -> 8 independent row gathers in flight.
template<int MODE>
__global__ __launch_bounds__(256) void k_agg(const bf16* __restrict__ H,
                                             const int* __restrict__ rptr,
                                             const int2* __restrict__ esw,
                                             const float* __restrict__ bias,
                                             void* __restrict__ out, int N) {
  const int wv = threadIdx.x >> 6;
  const int lane = threadIdx.x & 63;
  const int node = blockIdx.x * 8 + wv * 2 + (lane >> 5);
  if (node >= N) return;
  const int l16 = lane & 15;
  const int slot = (lane >> 4) & 1;
  const int p1 = rptr[node + 1];
  float a[8];
  #pragma unroll
  for (int j = 0; j < 8; ++j) a[j] = 0.f;

  int p = rptr[node] + slot;
  for (; p + 2 < p1; p += 4) {
    int2 e0 = esw[p];
    int2 e1 = esw[p + 2];
    bf16x8 h0 = *reinterpret_cast<const bf16x8*>(H + (size_t)e0.x * 128 + l16 * 8);
    bf16x8 h1 = *reinterpret_cast<const bf16x8*>(H + (size_t)e1.x * 128 + l16 * 8);
    float w0 = __int_as_float(e0.y), w1 = __int_as_float(e1.y);
    #pragma unroll
    for (int j = 0; j < 8; ++j)
      a[j] += w0 * (float)h0[j] + w1 * (float)h1[j];
  }
  if (p < p1) {
    int2 e0 = esw[p];
    bf16x8 h0 = *reinterpret_cast<const bf16x8*>(H + (size_t)e0.x * 128 + l16 * 8);
    float w0 = __int_as_float(e0.y);
    #pragma unroll
    for (int j = 0; j < 8; ++j)
      a[j] += w0 * (float)h0[j];
  }
  #pragma unroll
  for (int j = 0; j < 8; ++j) a[j] += __shfl_xor(a[j], 16);

  if ((lane & 16) == 0) {
    float4 b0 = *reinterpret_cast<const float4*>(bias + l16 * 8);
    float4 b1 = *reinterpret_cast<const float4*>(bias + l16 * 8 + 4);
    a[0] += b0.x; a[1] += b0.y; a[2] += b0.z; a[3] += b0.w;
    a[4] += b1.x; a[5] += b1.y; a[6] += b1.z; a[7] += b1.w;
    if (MODE == 0) {
      bf16x8 o;
      #pragma unroll
      for (int j = 0; j < 8; ++j) o[j] = (bf16)fmaxf(a[j], 0.f);
      *reinterpret_cast<bf16x8*>((bf16*)out + (size_t)node * 128 + l16 * 8) = o;
    } else {
      f32x4 o0 = {a[0], a[1], a[2], a[3]};
      f32x4 o1 = {a[4], a[5], a[6], a[7]};
      float* op = (float*)out + (size_t)node * 128 + l16 * 8;
      *reinterpret_cast<f32x4*>(op) = o0;
      *reinterpret_cast<f32x4*>(op + 4) = o1;
    }
  }
}

// ---------------- fc + log_softmax: one node per thread, fcw staged in LDS ----
__global__ __launch_bounds__(256) void k_fc_lsm(const float* __restrict__ emb,
                                                const float* __restrict__ fcwT,
                                                const float* __restrict__ fcb,
                                                float* __restrict__ out, int N) {
  __shared__ float wl[16 * 128];   // 8 KB, [c][k]
  __shared__ float fb[16];
  const int t = threadIdx.x;
  {
    const float4* s4 = reinterpret_cast<const float4*>(fcwT);
    float4* d4 = reinterpret_cast<float4*>(wl);
    d4[t] = s4[t];
    d4[t + 256] = s4[t + 256];
  }
  if (t < 16) fb[t] = fcb[t];
  __syncthreads();

  const int node = blockIdx.x * 256 + t;
  if (node >= N) return;
  const float4* er = reinterpret_cast<const float4*>(emb + (size_t)node * 128);

  float acc[16];
  #pragma unroll
  for (int c = 0; c < 16; ++c) acc[c] = fb[c];

  #pragma unroll 4
  for (int k4 = 0; k4 < 32; ++k4) {
    float4 e = er[k4];
    #pragma unroll
    for (int c = 0; c < 16; ++c) {
      float4 w = reinterpret_cast<const float4*>(wl + c * 128)[k4];
      acc[c] += e.x * w.x + e.y * w.y + e.z * w.z + e.w * w.w;
    }
  }

  float m = acc[0];
  #pragma unroll
  for (int c = 1; c < 16; ++c) m = fmaxf(m, acc[c]);
  float s = 0.f;
  #pragma unroll
  for (int c = 0; c < 16; ++c) s += __expf(acc[c] - m);
  float lse = m + __logf(s);
  float* op = out + (size_t)node * 16;
  #pragma unroll
  for (int c4 = 0; c4 < 4; ++c4) {
    f32x4 o = {acc[c4 * 4] - lse, acc[c4 * 4 + 1] - lse,
               acc[c4 * 4 + 2] - lse, acc[c4 * 4 + 3] - lse};
    *reinterpret_cast<f32x4*>(op + c4 * 4) = o;
  }
}

extern "C" void kernel_launch(void* const* d_in, const int* in_sizes, int n_in,
                              void* d_out, int out_size, void* d_ws, size_t ws_size,
                              hipStream_t stream) {
  const float* x   = (const float*)d_in[0];
  const float* ew  = (const float*)d_in[1];
  const float* W1  = (const float*)d_in[2];
  const float* b1  = (const float*)d_in[3];
  const float* W2  = (const float*)d_in[4];
  const float* b2  = (const float*)d_in[5];
  const float* W3  = (const float*)d_in[6];
  const float* b3  = (const float*)d_in[7];
  const float* fcw = (const float*)d_in[8];
  const float* fcb = (const float*)d_in[9];
  const int*   ei  = (const int*)d_in[10];

  const int N = in_sizes[0] / D_IN;     // 50000
  const int E = in_sizes[1];            // 625000
  const int* srcI = ei;
  const int* dstI = ei + E;

  char* ws = (char*)d_ws;
  size_t o = 0;
  auto take = [&](size_t b) -> char* {
    char* p = ws + o;
    o += (b + 255) & ~(size_t)255;
    return p;
  };
  bf16*  hb0  = (bf16*)take((size_t)N * 128 * 2);
  bf16*  hb1  = (bf16*)take((size_t)N * 128 * 2);
  bf16*  Bp1  = (bf16*)take((size_t)D_IN * 128 * 2);
  bf16*  Bp2  = (bf16*)take((size_t)D_HID * 128 * 2);
  bf16*  Bp3  = (bf16*)take((size_t)D_HID * 128 * 2);
  float* fcwT = (float*)take((size_t)2048 * 4);
  int*   deg  = (int*)take((size_t)N * 4);
  int*   rptr = (int*)take((size_t)(N + 1) * 4);
  int*   cur  = (int*)take((size_t)N * 4);
  int*   bsum = (int*)take(4096);
  int*   boff = (int*)take(4096);
  int2*  esw  = (int2*)take((size_t)E * 8);
  (void)ws_size; (void)n_in; (void)out_size;

  k_prep<<<256, 256, 0, stream>>>(W1, W2, W3, fcw, Bp1, Bp2, Bp3, fcwT, deg, N);

  int eb  = (E + 255) / 256;
  int nch = (N + 511) / 512;
  k_hist<<<eb, 256, 0, stream>>>(dstI, E, deg);
  k_blocksum<<<nch, 512, 0, stream>>>(deg, N, bsum);
  k_scan_partials<<<1, 128, 0, stream>>>(bsum, nch, boff, rptr, N, E);
  k_scan_final<<<nch, 512, 0, stream>>>(deg, N, boff, rptr, cur);
  k_scatter<<<eb, 256, 0, stream>>>(srcI, dstI, ew, E, cur, esw);

  float* emb = (float*)d_out;
  float* lsm = emb + (size_t)N * 128;
  int gb2 = (N + 127) / 128;
  int ab = (N + 7) / 8;

  k_gemm2<D_IN, true><<<gb2, 512, 0, stream>>>(x, Bp1, hb0, N);
  k_agg<0><<<ab, 256, 0, stream>>>(hb0, rptr, esw, b1, hb1, N);
  k_gemm2<D_HID, false><<<gb2, 512, 0, stream>>>(hb1, Bp2, hb0, N);
  k_agg<0><<<ab, 256, 0, stream>>>(hb0, rptr, esw, b2, hb1, N);
  k_gemm2<D_HID, false><<<gb2, 512, 0, stream>>>(hb1, Bp3, hb0, N);
  k_agg<1><<<ab, 256, 0, stream>>>(hb0, rptr, esw, b3, emb, N);
  k_fc_lsm<<<(N + 255) / 256, 256, 0, stream>>>(emb, fcwT, fcb, lsm, N);
}